// Round 1
// baseline (21405.052 us; speedup 1.0000x reference)
//
#include <hip/hip_runtime.h>
#include <hip/hip_bf16.h>
#include <math.h>

// Model dims
#define VV 50257
#define DD 512
#define HH 8
#define KK 64
#define FF 2048
#define EE 4
#define LL 128
#define BB 8
#define SS 512
#define NT (BB*SS)   // 4096 tokens

// ---------------------------------------------------------------------------
// Embedding gather (optionally masked by routing): out[t,:] = table[id,:]
// grid 4096 blocks x 128 threads, one float4 per thread
__global__ __launch_bounds__(128) void embed_gather(
    const int* __restrict__ ids, const int* __restrict__ route, int expert,
    const float* __restrict__ table, float* __restrict__ out) {
  int t = blockIdx.x;
  int id = ids[t];
  if (expert >= 0) id = (route[t] == expert) ? id : 0;
  const float4* src = (const float4*)(table + (size_t)id * DD);
  float4* dst = (float4*)(out + (size_t)t * DD);
  dst[threadIdx.x] = src[threadIdx.x];
}

// ---------------------------------------------------------------------------
// fp32 SGEMM: C[M,N] = A[M,K] @ B[K,N] (+ bias) (+= if ACCUM)
// BM=128, BN=64, BK=16, 256 threads, each thread 8x4 outputs.
template<bool ACCUM, bool BIAS>
__global__ __launch_bounds__(256) void sgemm(
    const float* __restrict__ A, const float* __restrict__ Bm,
    const float* __restrict__ bias, float* __restrict__ C,
    int M, int N, int Kd) {
  __shared__ float As[16][128];
  __shared__ float Bs[16][64];
  int tid = threadIdx.x;
  int bm = blockIdx.y * 128, bn = blockIdx.x * 64;
  int ty = tid >> 4, tx = tid & 15;         // 16x16 thread grid
  int arow = tid >> 2, akq = tid & 3;       // A loader: rows arow, arow+64
  int brow = tid >> 4, bnq = tid & 15;      // B loader

  float acc[8][4];
#pragma unroll
  for (int i = 0; i < 8; i++)
#pragma unroll
    for (int j = 0; j < 4; j++) acc[i][j] = 0.f;

  for (int kt = 0; kt < Kd; kt += 16) {
    float4 a0 = *(const float4*)&A[(size_t)(bm + arow) * Kd + kt + akq * 4];
    float4 a1 = *(const float4*)&A[(size_t)(bm + arow + 64) * Kd + kt + akq * 4];
    float4 b0 = *(const float4*)&Bm[(size_t)(kt + brow) * N + bn + bnq * 4];
    __syncthreads();
    As[akq * 4 + 0][arow] = a0.x; As[akq * 4 + 1][arow] = a0.y;
    As[akq * 4 + 2][arow] = a0.z; As[akq * 4 + 3][arow] = a0.w;
    As[akq * 4 + 0][arow + 64] = a1.x; As[akq * 4 + 1][arow + 64] = a1.y;
    As[akq * 4 + 2][arow + 64] = a1.z; As[akq * 4 + 3][arow + 64] = a1.w;
    *(float4*)&Bs[brow][bnq * 4] = b0;
    __syncthreads();
#pragma unroll
    for (int k = 0; k < 16; k++) {
      float4 a0v = *(const float4*)&As[k][ty * 4];
      float4 a1v = *(const float4*)&As[k][64 + ty * 4];
      float4 bv  = *(const float4*)&Bs[k][tx * 4];
      float av[8] = {a0v.x, a0v.y, a0v.z, a0v.w, a1v.x, a1v.y, a1v.z, a1v.w};
      float bb[4] = {bv.x, bv.y, bv.z, bv.w};
#pragma unroll
      for (int i = 0; i < 8; i++)
#pragma unroll
        for (int j = 0; j < 4; j++) acc[i][j] += av[i] * bb[j];
    }
  }

  int cn = bn + tx * 4;
  float4 bias4 = make_float4(0.f, 0.f, 0.f, 0.f);
  if (BIAS) bias4 = *(const float4*)&bias[cn];
#pragma unroll
  for (int i = 0; i < 8; i++) {
    int r = bm + ((i < 4) ? (ty * 4 + i) : (64 + ty * 4 + i - 4));
    float* cp = &C[(size_t)r * N + cn];
    float4 val;
    val.x = acc[i][0] + bias4.x; val.y = acc[i][1] + bias4.y;
    val.z = acc[i][2] + bias4.z; val.w = acc[i][3] + bias4.w;
    if (ACCUM) {
      float4 old = *(const float4*)cp;
      val.x += old.x; val.y += old.y; val.z += old.z; val.w += old.w;
    }
    *(float4*)cp = val;
  }
}

// ---------------------------------------------------------------------------
// MHA core: out[b,q,h,:] = softmax(q.k^T/8) @ v   for one (b,h,32-q-row) tile.
// q,k,v,out layout: [(b*S+s)*512 + h*64 + kk]
// grid (S/32, H, B), 256 threads.
__global__ __launch_bounds__(256) void attention(
    const float* __restrict__ q, const float* __restrict__ k,
    const float* __restrict__ v, float* __restrict__ out) {
  __shared__ float Qs[32][64];
  __shared__ float Sc[32][513];   // pad: stride 513 -> bank = (row + col) % 32
  __shared__ float KV[64][65];    // pad: stride 65
  __shared__ float red[32][8];
  __shared__ float rowm[32];
  __shared__ float rowl[32];

  int t = threadIdx.x;
  int q0 = blockIdx.x * 32;
  int h = blockIdx.y, b = blockIdx.z;
  size_t base = ((size_t)b * SS) * DD + h * KK;

  // load Q tile (32x64)
#pragma unroll
  for (int it = 0; it < 2; it++) {
    int idx = it * 256 + t; int r = idx >> 4, cq = idx & 15;
    *(float4*)&Qs[r][cq * 4] = *(const float4*)&q[base + (size_t)(q0 + r) * DD + cq * 4];
  }

  // scores
  for (int st = 0; st < 8; st++) {
    __syncthreads();
#pragma unroll
    for (int it = 0; it < 4; it++) {
      int idx = it * 256 + t; int r = idx >> 4, cq = idx & 15;
      float4 kv = *(const float4*)&k[base + (size_t)(st * 64 + r) * DD + cq * 4];
      KV[r][cq * 4 + 0] = kv.x; KV[r][cq * 4 + 1] = kv.y;
      KV[r][cq * 4 + 2] = kv.z; KV[r][cq * 4 + 3] = kv.w;
    }
    __syncthreads();
#pragma unroll
    for (int jj = 0; jj < 8; jj++) {
      int sidx = jj * 256 + t; int qr = sidx >> 6, sc = sidx & 63;
      float dot = 0.f;
#pragma unroll
      for (int c4 = 0; c4 < 16; c4++) {
        float4 qv = *(const float4*)&Qs[qr][c4 * 4];
        dot += qv.x * KV[sc][c4 * 4 + 0] + qv.y * KV[sc][c4 * 4 + 1]
             + qv.z * KV[sc][c4 * 4 + 2] + qv.w * KV[sc][c4 * 4 + 3];
      }
      Sc[qr][st * 64 + sc] = dot * 0.125f;
    }
  }
  __syncthreads();

  // softmax over 512 cols: row = t&31, seg = t>>5 (64 cols per thread)
  {
    int row = t & 31, seg = t >> 5;
    float m = -1e30f;
    for (int i = 0; i < 64; i++) m = fmaxf(m, Sc[row][seg * 64 + i]);
    red[row][seg] = m;
    __syncthreads();
    if (t < 32) {
      float mm = red[t][0];
#pragma unroll
      for (int s2 = 1; s2 < 8; s2++) mm = fmaxf(mm, red[t][s2]);
      rowm[t] = mm;
    }
    __syncthreads();
    float mm = rowm[row];
    float l = 0.f;
    for (int i = 0; i < 64; i++) {
      float e = expf(Sc[row][seg * 64 + i] - mm);
      Sc[row][seg * 64 + i] = e;
      l += e;
    }
    red[row][seg] = l;
    __syncthreads();
    if (t < 32) {
      float s = 0.f;
#pragma unroll
      for (int s2 = 0; s2 < 8; s2++) s += red[t][s2];
      rowl[t] = s;
    }
  }

  // P @ V: qq = t>>3 (0..31), kg = t&7 (8 head-dims each)
  int qq = t >> 3, kg = t & 7;
  float acc[8];
#pragma unroll
  for (int j = 0; j < 8; j++) acc[j] = 0.f;
  for (int st = 0; st < 8; st++) {
    __syncthreads();
#pragma unroll
    for (int it = 0; it < 4; it++) {
      int idx = it * 256 + t; int r = idx >> 4, cq = idx & 15;
      float4 vv = *(const float4*)&v[base + (size_t)(st * 64 + r) * DD + cq * 4];
      KV[r][cq * 4 + 0] = vv.x; KV[r][cq * 4 + 1] = vv.y;
      KV[r][cq * 4 + 2] = vv.z; KV[r][cq * 4 + 3] = vv.w;
    }
    __syncthreads();
    for (int s = 0; s < 64; s++) {
      float p = Sc[qq][st * 64 + s];
#pragma unroll
      for (int jv = 0; jv < 8; jv++) acc[jv] += p * KV[s][kg * 8 + jv];
    }
  }
  float inv = 1.f / rowl[qq];
  float4 o0 = make_float4(acc[0] * inv, acc[1] * inv, acc[2] * inv, acc[3] * inv);
  float4 o1 = make_float4(acc[4] * inv, acc[5] * inv, acc[6] * inv, acc[7] * inv);
  size_t ob = base + (size_t)(q0 + qq) * DD + kg * 8;
  *(float4*)&out[ob] = o0;
  *(float4*)&out[ob + 4] = o1;
}

// ---------------------------------------------------------------------------
// Gating + argmax routing: one wave per token
__global__ __launch_bounds__(256) void gating_argmax(
    const float* __restrict__ h, const float* __restrict__ wg,
    int* __restrict__ route) {
  int t = blockIdx.x * 4 + (threadIdx.x >> 6);
  int lane = threadIdx.x & 63;
  const float* hr = h + (size_t)t * DD;
  float g0 = 0, g1 = 0, g2 = 0, g3 = 0;
#pragma unroll
  for (int i = 0; i < 8; i++) {
    float x = hr[lane * 8 + i];
    const float* wr = wg + (size_t)(lane * 8 + i) * EE;
    g0 += x * wr[0]; g1 += x * wr[1]; g2 += x * wr[2]; g3 += x * wr[3];
  }
#pragma unroll
  for (int off = 32; off; off >>= 1) {
    g0 += __shfl_down(g0, off);
    g1 += __shfl_down(g1, off);
    g2 += __shfl_down(g2, off);
    g3 += __shfl_down(g3, off);
  }
  if (lane == 0) {
    float best = g0; int bi = 0;
    if (g1 > best) { best = g1; bi = 1; }
    if (g2 > best) { best = g2; bi = 2; }
    if (g3 > best) { best = g3; bi = 3; }
    route[t] = bi;
  }
}

// ---------------------------------------------------------------------------
// LSTM recurrent scan. zx = x@W_x + b precomputed [N, 4L]. One block per batch
// row, 512 threads; each thread owns one z column; W_h column in registers.
__device__ __forceinline__ float sigmoidf_(float x) { return 1.f / (1.f + expf(-x)); }

__global__ __launch_bounds__(512) void lstm_scan(
    const float* __restrict__ zx, const float* __restrict__ lstm_w,
    float* __restrict__ hout) {
  int b = blockIdx.x;
  int j = threadIdx.x;
  __shared__ float hs[LL];
  __shared__ float zs[4 * LL];
  float wh[LL];
#pragma unroll
  for (int l = 0; l < LL; l++) wh[l] = lstm_w[(size_t)(DD + l) * (4 * LL) + j];
  float c = 0.f;
  if (j < LL) hs[j] = 0.f;
  __syncthreads();
  for (int t = 0; t < SS; t++) {
    float acc = zx[(size_t)(b * SS + t) * (4 * LL) + j];
#pragma unroll
    for (int l = 0; l < LL; l++) acc += hs[l] * wh[l];
    zs[j] = acc;
    __syncthreads();
    if (j < LL) {
      float iv = zs[j], gv = zs[j + LL], fv = zs[j + 2 * LL], ov = zs[j + 3 * LL];
      c = sigmoidf_(fv + 1.f) * c + sigmoidf_(iv) * tanhf(gv);
      float h2 = sigmoidf_(ov) * tanhf(c);
      hs[j] = h2;
      hout[(size_t)(b * SS + t) * LL + j] = h2;
    }
    __syncthreads();
  }
}

// ---------------------------------------------------------------------------
// Final head: out[t] = lstm_out[t,:] @ wd + bd. One wave per token.
__global__ __launch_bounds__(256) void final_proj(
    const float* __restrict__ lo, const float* __restrict__ wd,
    const float* __restrict__ bd, float* __restrict__ out) {
  int t = blockIdx.x * 4 + (threadIdx.x >> 6);
  int lane = threadIdx.x & 63;
  float s = lo[(size_t)t * LL + lane] * wd[lane]
          + lo[(size_t)t * LL + 64 + lane] * wd[64 + lane];
#pragma unroll
  for (int off = 32; off; off >>= 1) s += __shfl_down(s, off);
  if (lane == 0) out[t] = s + bd[0];
}

// ---------------------------------------------------------------------------
extern "C" void kernel_launch(void* const* d_in, const int* in_sizes, int n_in,
                              void* d_out, int out_size, void* d_ws, size_t ws_size,
                              hipStream_t stream) {
  const int*   ids    = (const int*)  d_in[0];
  const float* embed  = (const float*)d_in[1];
  const float* wq     = (const float*)d_in[2];
  const float* wk     = (const float*)d_in[3];
  const float* wv     = (const float*)d_in[4];
  const float* wo     = (const float*)d_in[5];
  const float* w1     = (const float*)d_in[6];
  const float* b1     = (const float*)d_in[7];
  const float* w2     = (const float*)d_in[8];
  const float* b2     = (const float*)d_in[9];
  const float* wg     = (const float*)d_in[10];
  const float* e_embed= (const float*)d_in[11];
  const float* e_wq   = (const float*)d_in[12];
  const float* e_wk   = (const float*)d_in[13];
  const float* e_wv   = (const float*)d_in[14];
  const float* e_wo   = (const float*)d_in[15];
  const float* e_w1   = (const float*)d_in[16];
  const float* e_b1   = (const float*)d_in[17];
  const float* e_w2   = (const float*)d_in[18];
  const float* e_b2   = (const float*)d_in[19];
  const float* a_wq   = (const float*)d_in[20];
  const float* a_wk   = (const float*)d_in[21];
  const float* a_wv   = (const float*)d_in[22];
  const float* a_wv_  = a_wv; (void)a_wv_;
  const float* a_wo   = (const float*)d_in[23];
  const float* lstm_w = (const float*)d_in[24];
  const float* lstm_b = (const float*)d_in[25];
  const float* wd     = (const float*)d_in[26];
  const float* bd     = (const float*)d_in[27];
  float* out = (float*)d_out;

  const size_t TD = (size_t)NT * DD;  // 2,097,152
  float* ws  = (float*)d_ws;
  float* Ab  = ws;
  float* Qb  = ws + 1 * TD;
  float* Kb  = ws + 2 * TD;
  float* Vb  = ws + 3 * TD;
  float* Tb  = ws + 4 * TD;
  float* AGG = ws + 5 * TD;
  float* MID = ws + 6 * TD;           // NT*FF = 8,388,608 floats
  float* ZX  = MID;                   // reused after experts
  float* LOUT= MID + TD;
  int*   route = (int*)(ws + 6 * TD + (size_t)NT * FF);

  dim3 blk256(256), blk128(128), blk512(512);
  dim3 gN512(DD / 64, NT / 128);      // N=512 GEMMs
  dim3 gN2048(FF / 64, NT / 128);     // N=2048 GEMMs
  dim3 gAttn(SS / 32, HH, BB);

  // ---------------- base block ----------------
  embed_gather<<<NT, blk128, 0, stream>>>(ids, nullptr, -1, embed, Ab);
  sgemm<false, false><<<gN512, blk256, 0, stream>>>(Ab, wq, nullptr, Qb, NT, DD, DD);
  sgemm<false, false><<<gN512, blk256, 0, stream>>>(Ab, wk, nullptr, Kb, NT, DD, DD);
  sgemm<false, false><<<gN512, blk256, 0, stream>>>(Ab, wv, nullptr, Vb, NT, DD, DD);
  attention<<<gAttn, blk256, 0, stream>>>(Qb, Kb, Vb, Tb);
  sgemm<false, false><<<gN512, blk256, 0, stream>>>(Tb, wo, nullptr, Ab, NT, DD, DD);
  sgemm<false, true ><<<gN2048, blk256, 0, stream>>>(Ab, w1, b1, MID, NT, FF, DD);
  sgemm<false, true ><<<gN512, blk256, 0, stream>>>(MID, w2, b2, Qb, NT, DD, FF); // h -> Qb
  gating_argmax<<<NT / 4, blk256, 0, stream>>>(Qb, wg, route);

  hipMemsetAsync(AGG, 0, TD * sizeof(float), stream);

  // ---------------- experts ----------------
  for (int e = 0; e < EE; e++) {
    const size_t wOff = (size_t)e * DD * DD;
    embed_gather<<<NT, blk128, 0, stream>>>(ids, route, e,
        e_embed + (size_t)e * VV * DD, Ab);
    sgemm<false, false><<<gN512, blk256, 0, stream>>>(Ab, e_wq + wOff, nullptr, Qb, NT, DD, DD);
    sgemm<false, false><<<gN512, blk256, 0, stream>>>(Ab, e_wk + wOff, nullptr, Kb, NT, DD, DD);
    sgemm<false, false><<<gN512, blk256, 0, stream>>>(Ab, e_wv + wOff, nullptr, Vb, NT, DD, DD);
    attention<<<gAttn, blk256, 0, stream>>>(Qb, Kb, Vb, Tb);
    sgemm<false, false><<<gN512, blk256, 0, stream>>>(Tb, e_wo + wOff, nullptr, Ab, NT, DD, DD);
    sgemm<false, true ><<<gN2048, blk256, 0, stream>>>(Ab, e_w1 + (size_t)e * DD * FF,
        e_b1 + (size_t)e * FF, MID, NT, FF, DD);
    sgemm<true,  true ><<<gN512, blk256, 0, stream>>>(MID, e_w2 + (size_t)e * FF * DD,
        e_b2 + (size_t)e * DD, AGG, NT, DD, FF);
  }

  // ---------------- final attention ----------------
  sgemm<false, false><<<gN512, blk256, 0, stream>>>(AGG, a_wq, nullptr, Qb, NT, DD, DD);
  sgemm<false, false><<<gN512, blk256, 0, stream>>>(AGG, a_wk, nullptr, Kb, NT, DD, DD);
  sgemm<false, false><<<gN512, blk256, 0, stream>>>(AGG, a_wv, nullptr, Vb, NT, DD, DD);
  attention<<<gAttn, blk256, 0, stream>>>(Qb, Kb, Vb, Tb);
  sgemm<false, false><<<gN512, blk256, 0, stream>>>(Tb, a_wo, nullptr, Ab, NT, DD, DD);

  // ---------------- LSTM ----------------
  // input projection: uses first DD rows of lstm_w (row stride 4L == 512)
  sgemm<false, true ><<<gN512, blk256, 0, stream>>>(Ab, lstm_w, lstm_b, ZX, NT, 4 * LL, DD);
  lstm_scan<<<BB, blk512, 0, stream>>>(ZX, lstm_w, LOUT);

  // ---------------- head ----------------
  final_proj<<<NT / 4, blk256, 0, stream>>>(LOUT, wd, bd, out);
}

// Round 2
// 4888.643 us; speedup vs baseline: 4.3785x; 4.3785x over previous
//
#include <hip/hip_runtime.h>
#include <hip/hip_bf16.h>
#include <math.h>

// Model dims
#define VV 50257
#define DD 512
#define HH 8
#define KK 64
#define FF 2048
#define EE 4
#define LL 128
#define BB 8
#define SS 512
#define NT (BB*SS)   // 4096 tokens

// ---------------------------------------------------------------------------
// Embedding gather (optionally masked by routing): out[t,:] = table[id,:]
// grid 4096 blocks x 128 threads, one float4 per thread
__global__ __launch_bounds__(128) void embed_gather(
    const int* __restrict__ ids, const int* __restrict__ route, int expert,
    const float* __restrict__ table, float* __restrict__ out) {
  int t = blockIdx.x;
  int id = ids[t];
  if (expert >= 0) id = (route[t] == expert) ? id : 0;
  const float4* src = (const float4*)(table + (size_t)id * DD);
  float4* dst = (float4*)(out + (size_t)t * DD);
  dst[threadIdx.x] = src[threadIdx.x];
}

// ---------------------------------------------------------------------------
// fp32 SGEMM: C[M,N] = A[M,K] @ B[K,N] (+ bias) (+= if ACCUM)
// BM=128, BN=64, BK=16, 256 threads, each thread 8x4 outputs.
template<bool ACCUM, bool BIAS>
__global__ __launch_bounds__(256) void sgemm(
    const float* __restrict__ A, const float* __restrict__ Bm,
    const float* __restrict__ bias, float* __restrict__ C,
    int M, int N, int Kd) {
  __shared__ float As[16][128];
  __shared__ float Bs[16][64];
  int tid = threadIdx.x;
  int bm = blockIdx.y * 128, bn = blockIdx.x * 64;
  int ty = tid >> 4, tx = tid & 15;         // 16x16 thread grid
  int arow = tid >> 2, akq = tid & 3;       // A loader: rows arow, arow+64
  int brow = tid >> 4, bnq = tid & 15;      // B loader

  float acc[8][4];
#pragma unroll
  for (int i = 0; i < 8; i++)
#pragma unroll
    for (int j = 0; j < 4; j++) acc[i][j] = 0.f;

  for (int kt = 0; kt < Kd; kt += 16) {
    float4 a0 = *(const float4*)&A[(size_t)(bm + arow) * Kd + kt + akq * 4];
    float4 a1 = *(const float4*)&A[(size_t)(bm + arow + 64) * Kd + kt + akq * 4];
    float4 b0 = *(const float4*)&Bm[(size_t)(kt + brow) * N + bn + bnq * 4];
    __syncthreads();
    As[akq * 4 + 0][arow] = a0.x; As[akq * 4 + 1][arow] = a0.y;
    As[akq * 4 + 2][arow] = a0.z; As[akq * 4 + 3][arow] = a0.w;
    As[akq * 4 + 0][arow + 64] = a1.x; As[akq * 4 + 1][arow + 64] = a1.y;
    As[akq * 4 + 2][arow + 64] = a1.z; As[akq * 4 + 3][arow + 64] = a1.w;
    *(float4*)&Bs[brow][bnq * 4] = b0;
    __syncthreads();
#pragma unroll
    for (int k = 0; k < 16; k++) {
      float4 a0v = *(const float4*)&As[k][ty * 4];
      float4 a1v = *(const float4*)&As[k][64 + ty * 4];
      float4 bv  = *(const float4*)&Bs[k][tx * 4];
      float av[8] = {a0v.x, a0v.y, a0v.z, a0v.w, a1v.x, a1v.y, a1v.z, a1v.w};
      float bb[4] = {bv.x, bv.y, bv.z, bv.w};
#pragma unroll
      for (int i = 0; i < 8; i++)
#pragma unroll
        for (int j = 0; j < 4; j++) acc[i][j] += av[i] * bb[j];
    }
  }

  int cn = bn + tx * 4;
  float4 bias4 = make_float4(0.f, 0.f, 0.f, 0.f);
  if (BIAS) bias4 = *(const float4*)&bias[cn];
#pragma unroll
  for (int i = 0; i < 8; i++) {
    int r = bm + ((i < 4) ? (ty * 4 + i) : (64 + ty * 4 + i - 4));
    float* cp = &C[(size_t)r * N + cn];
    float4 val;
    val.x = acc[i][0] + bias4.x; val.y = acc[i][1] + bias4.y;
    val.z = acc[i][2] + bias4.z; val.w = acc[i][3] + bias4.w;
    if (ACCUM) {
      float4 old = *(const float4*)cp;
      val.x += old.x; val.y += old.y; val.z += old.z; val.w += old.w;
    }
    *(float4*)cp = val;
  }
}

// ---------------------------------------------------------------------------
// Flash-style MHA: one block = 64 q-rows of one (b,h). 128 threads.
// Iterate 8 k-tiles of 64; S-tile & P-tile live in registers (8x4/thread),
// online softmax with shfl row-reductions; all LDS reads are ds_read_b128.
// LDS: QsT + KV(shared K^T/V) + PsT = 3*64*68*4 = 52224 B -> 3 blocks/CU.
// q,k,v,out layout: [(b*S+s)*512 + h*64 + d]
__global__ __launch_bounds__(128) void attention(
    const float* __restrict__ q, const float* __restrict__ k,
    const float* __restrict__ v, float* __restrict__ out) {
  __shared__ float QsT[64][68];   // [kdim][qrow]
  __shared__ float KV[64][68];    // phase 1: K^T [kdim][srow]; phase 2: V [srow][d]
  __shared__ float PsT[64][68];   // [srow][qrow]

  int t = threadIdx.x;
  int tx = t & 15, ty = t >> 4;   // 16 x 8 thread grid; thread tile 8 rows x 4 cols
  int q0 = blockIdx.x * 64;
  int h = blockIdx.y, b = blockIdx.z;
  size_t base = ((size_t)b * SS) * DD + (size_t)h * KK;

  // load Q tile (64x64), transposed into QsT[k][row]
#pragma unroll
  for (int it = 0; it < 8; it++) {
    int idx = it * 128 + t; int r = idx >> 4, c4 = idx & 15;
    float4 qv = *(const float4*)&q[base + (size_t)(q0 + r) * DD + c4 * 4];
    QsT[c4 * 4 + 0][r] = qv.x; QsT[c4 * 4 + 1][r] = qv.y;
    QsT[c4 * 4 + 2][r] = qv.z; QsT[c4 * 4 + 3][r] = qv.w;
  }

  float acc[8][4];
  float m_run[8], l_run[8];
#pragma unroll
  for (int i = 0; i < 8; i++) {
    m_run[i] = -1e30f; l_run[i] = 0.f;
#pragma unroll
    for (int j = 0; j < 4; j++) acc[i][j] = 0.f;
  }

  for (int st = 0; st < 8; st++) {
    __syncthreads();  // prev-iter KV/PsT reads done (also orders QsT at st=0)
    // K tile transposed into KV[k][srow]
#pragma unroll
    for (int it = 0; it < 8; it++) {
      int idx = it * 128 + t; int r = idx >> 4, c4 = idx & 15;
      float4 kv4 = *(const float4*)&k[base + (size_t)(st * 64 + r) * DD + c4 * 4];
      KV[c4 * 4 + 0][r] = kv4.x; KV[c4 * 4 + 1][r] = kv4.y;
      KV[c4 * 4 + 2][r] = kv4.z; KV[c4 * 4 + 3][r] = kv4.w;
    }
    __syncthreads();

    // S = (Q K^T) for this tile: 8x4 per thread
    float s[8][4];
#pragma unroll
    for (int i = 0; i < 8; i++)
#pragma unroll
      for (int j = 0; j < 4; j++) s[i][j] = 0.f;
    for (int kk = 0; kk < 64; kk++) {
      float4 a0 = *(const float4*)&QsT[kk][ty * 8];
      float4 a1 = *(const float4*)&QsT[kk][ty * 8 + 4];
      float4 bv = *(const float4*)&KV[kk][tx * 4];
      float aa[8] = {a0.x, a0.y, a0.z, a0.w, a1.x, a1.y, a1.z, a1.w};
      float bb[4] = {bv.x, bv.y, bv.z, bv.w};
#pragma unroll
      for (int i = 0; i < 8; i++)
#pragma unroll
        for (int j = 0; j < 4; j++) s[i][j] += aa[i] * bb[j];
    }

    // online softmax: rows owned by threads sharing ty (16 lanes, low 4 bits)
#pragma unroll
    for (int i = 0; i < 8; i++) {
#pragma unroll
      for (int j = 0; j < 4; j++) s[i][j] *= 0.125f;
      float rm = fmaxf(fmaxf(s[i][0], s[i][1]), fmaxf(s[i][2], s[i][3]));
      rm = fmaxf(rm, __shfl_xor(rm, 1));
      rm = fmaxf(rm, __shfl_xor(rm, 2));
      rm = fmaxf(rm, __shfl_xor(rm, 4));
      rm = fmaxf(rm, __shfl_xor(rm, 8));
      float mnew = fmaxf(m_run[i], rm);
      float alpha = expf(m_run[i] - mnew);
      m_run[i] = mnew;
      float rs = 0.f;
#pragma unroll
      for (int j = 0; j < 4; j++) {
        float p = expf(s[i][j] - mnew);
        s[i][j] = p; rs += p;
      }
      rs += __shfl_xor(rs, 1); rs += __shfl_xor(rs, 2);
      rs += __shfl_xor(rs, 4); rs += __shfl_xor(rs, 8);
      l_run[i] = l_run[i] * alpha + rs;
#pragma unroll
      for (int j = 0; j < 4; j++) acc[i][j] *= alpha;
    }

    // write P^T for the PV microkernel
#pragma unroll
    for (int i = 0; i < 8; i++)
#pragma unroll
      for (int j = 0; j < 4; j++)
        PsT[tx * 4 + j][ty * 8 + i] = s[i][j];
    __syncthreads();  // PsT written; KV (K^T) reads done

    // V tile into KV[srow][d]
#pragma unroll
    for (int it = 0; it < 8; it++) {
      int idx = it * 128 + t; int r = idx >> 4, c4 = idx & 15;
      *(float4*)&KV[r][c4 * 4] =
          *(const float4*)&v[base + (size_t)(st * 64 + r) * DD + c4 * 4];
    }
    __syncthreads();

    // O += P V
    for (int jj = 0; jj < 64; jj++) {
      float4 a0 = *(const float4*)&PsT[jj][ty * 8];
      float4 a1 = *(const float4*)&PsT[jj][ty * 8 + 4];
      float4 bv = *(const float4*)&KV[jj][tx * 4];
      float aa[8] = {a0.x, a0.y, a0.z, a0.w, a1.x, a1.y, a1.z, a1.w};
      float bb[4] = {bv.x, bv.y, bv.z, bv.w};
#pragma unroll
      for (int i = 0; i < 8; i++)
#pragma unroll
        for (int j = 0; j < 4; j++) acc[i][j] += aa[i] * bb[j];
    }
  }

  // epilogue: normalize and store
#pragma unroll
  for (int i = 0; i < 8; i++) {
    float inv = 1.f / l_run[i];
    float4 o = make_float4(acc[i][0] * inv, acc[i][1] * inv,
                           acc[i][2] * inv, acc[i][3] * inv);
    *(float4*)&out[base + (size_t)(q0 + ty * 8 + i) * DD + tx * 4] = o;
  }
}

// ---------------------------------------------------------------------------
// Gating + argmax routing: one wave per token
__global__ __launch_bounds__(256) void gating_argmax(
    const float* __restrict__ h, const float* __restrict__ wg,
    int* __restrict__ route) {
  int t = blockIdx.x * 4 + (threadIdx.x >> 6);
  int lane = threadIdx.x & 63;
  const float* hr = h + (size_t)t * DD;
  float g0 = 0, g1 = 0, g2 = 0, g3 = 0;
#pragma unroll
  for (int i = 0; i < 8; i++) {
    float x = hr[lane * 8 + i];
    const float* wr = wg + (size_t)(lane * 8 + i) * EE;
    g0 += x * wr[0]; g1 += x * wr[1]; g2 += x * wr[2]; g3 += x * wr[3];
  }
#pragma unroll
  for (int off = 32; off; off >>= 1) {
    g0 += __shfl_down(g0, off);
    g1 += __shfl_down(g1, off);
    g2 += __shfl_down(g2, off);
    g3 += __shfl_down(g3, off);
  }
  if (lane == 0) {
    float best = g0; int bi = 0;
    if (g1 > best) { best = g1; bi = 1; }
    if (g2 > best) { best = g2; bi = 2; }
    if (g3 > best) { best = g3; bi = 3; }
    route[t] = bi;
  }
}

// ---------------------------------------------------------------------------
// LSTM recurrent scan. zx = x@W_x + b precomputed [N, 4L]. One block per batch
// row, 512 threads; each thread owns one z column; W_h column in registers.
__device__ __forceinline__ float sigmoidf_(float x) { return 1.f / (1.f + expf(-x)); }

__global__ __launch_bounds__(512) void lstm_scan(
    const float* __restrict__ zx, const float* __restrict__ lstm_w,
    float* __restrict__ hout) {
  int b = blockIdx.x;
  int j = threadIdx.x;
  __shared__ float hs[LL];
  __shared__ float zs[4 * LL];
  float wh[LL];
#pragma unroll
  for (int l = 0; l < LL; l++) wh[l] = lstm_w[(size_t)(DD + l) * (4 * LL) + j];
  float c = 0.f;
  if (j < LL) hs[j] = 0.f;
  __syncthreads();
  for (int t = 0; t < SS; t++) {
    float acc = zx[(size_t)(b * SS + t) * (4 * LL) + j];
#pragma unroll
    for (int l = 0; l < LL; l++) acc += hs[l] * wh[l];
    zs[j] = acc;
    __syncthreads();
    if (j < LL) {
      float iv = zs[j], gv = zs[j + LL], fv = zs[j + 2 * LL], ov = zs[j + 3 * LL];
      c = sigmoidf_(fv + 1.f) * c + sigmoidf_(iv) * tanhf(gv);
      float h2 = sigmoidf_(ov) * tanhf(c);
      hs[j] = h2;
      hout[(size_t)(b * SS + t) * LL + j] = h2;
    }
    __syncthreads();
  }
}

// ---------------------------------------------------------------------------
// Final head: out[t] = lstm_out[t,:] @ wd + bd. One wave per token.
__global__ __launch_bounds__(256) void final_proj(
    const float* __restrict__ lo, const float* __restrict__ wd,
    const float* __restrict__ bd, float* __restrict__ out) {
  int t = blockIdx.x * 4 + (threadIdx.x >> 6);
  int lane = threadIdx.x & 63;
  float s = lo[(size_t)t * LL + lane] * wd[lane]
          + lo[(size_t)t * LL + 64 + lane] * wd[64 + lane];
#pragma unroll
  for (int off = 32; off; off >>= 1) s += __shfl_down(s, off);
  if (lane == 0) out[t] = s + bd[0];
}

// ---------------------------------------------------------------------------
extern "C" void kernel_launch(void* const* d_in, const int* in_sizes, int n_in,
                              void* d_out, int out_size, void* d_ws, size_t ws_size,
                              hipStream_t stream) {
  const int*   ids    = (const int*)  d_in[0];
  const float* embed  = (const float*)d_in[1];
  const float* wq     = (const float*)d_in[2];
  const float* wk     = (const float*)d_in[3];
  const float* wv     = (const float*)d_in[4];
  const float* wo     = (const float*)d_in[5];
  const float* w1     = (const float*)d_in[6];
  const float* b1     = (const float*)d_in[7];
  const float* w2     = (const float*)d_in[8];
  const float* b2     = (const float*)d_in[9];
  const float* wg     = (const float*)d_in[10];
  const float* e_embed= (const float*)d_in[11];
  const float* e_wq   = (const float*)d_in[12];
  const float* e_wk   = (const float*)d_in[13];
  const float* e_wv   = (const float*)d_in[14];
  const float* e_wo   = (const float*)d_in[15];
  const float* e_w1   = (const float*)d_in[16];
  const float* e_b1   = (const float*)d_in[17];
  const float* e_w2   = (const float*)d_in[18];
  const float* e_b2   = (const float*)d_in[19];
  const float* a_wq   = (const float*)d_in[20];
  const float* a_wk   = (const float*)d_in[21];
  const float* a_wv   = (const float*)d_in[22];
  const float* a_wo   = (const float*)d_in[23];
  const float* lstm_w = (const float*)d_in[24];
  const float* lstm_b = (const float*)d_in[25];
  const float* wd     = (const float*)d_in[26];
  const float* bd     = (const float*)d_in[27];
  float* out = (float*)d_out;

  const size_t TD = (size_t)NT * DD;  // 2,097,152
  float* ws  = (float*)d_ws;
  float* Ab  = ws;
  float* Qb  = ws + 1 * TD;
  float* Kb  = ws + 2 * TD;
  float* Vb  = ws + 3 * TD;
  float* Tb  = ws + 4 * TD;
  float* AGG = ws + 5 * TD;
  float* MID = ws + 6 * TD;           // NT*FF = 8,388,608 floats
  float* ZX  = MID;                   // reused after experts
  float* LOUT= MID + TD;
  int*   route = (int*)(ws + 6 * TD + (size_t)NT * FF);

  dim3 blk256(256), blk128(128), blk512(512);
  dim3 gN512(DD / 64, NT / 128);      // N=512 GEMMs
  dim3 gN2048(FF / 64, NT / 128);     // N=2048 GEMMs
  dim3 gAttn(SS / 64, HH, BB);        // 8 x 8 x 8 = 512 blocks

  // ---------------- base block ----------------
  embed_gather<<<NT, blk128, 0, stream>>>(ids, nullptr, -1, embed, Ab);
  sgemm<false, false><<<gN512, blk256, 0, stream>>>(Ab, wq, nullptr, Qb, NT, DD, DD);
  sgemm<false, false><<<gN512, blk256, 0, stream>>>(Ab, wk, nullptr, Kb, NT, DD, DD);
  sgemm<false, false><<<gN512, blk256, 0, stream>>>(Ab, wv, nullptr, Vb, NT, DD, DD);
  attention<<<gAttn, blk128, 0, stream>>>(Qb, Kb, Vb, Tb);
  sgemm<false, false><<<gN512, blk256, 0, stream>>>(Tb, wo, nullptr, Ab, NT, DD, DD);
  sgemm<false, true ><<<gN2048, blk256, 0, stream>>>(Ab, w1, b1, MID, NT, FF, DD);
  sgemm<false, true ><<<gN512, blk256, 0, stream>>>(MID, w2, b2, Qb, NT, DD, FF); // h -> Qb
  gating_argmax<<<NT / 4, blk256, 0, stream>>>(Qb, wg, route);

  hipMemsetAsync(AGG, 0, TD * sizeof(float), stream);

  // ---------------- experts ----------------
  for (int e = 0; e < EE; e++) {
    const size_t wOff = (size_t)e * DD * DD;
    embed_gather<<<NT, blk128, 0, stream>>>(ids, route, e,
        e_embed + (size_t)e * VV * DD, Ab);
    sgemm<false, false><<<gN512, blk256, 0, stream>>>(Ab, e_wq + wOff, nullptr, Qb, NT, DD, DD);
    sgemm<false, false><<<gN512, blk256, 0, stream>>>(Ab, e_wk + wOff, nullptr, Kb, NT, DD, DD);
    sgemm<false, false><<<gN512, blk256, 0, stream>>>(Ab, e_wv + wOff, nullptr, Vb, NT, DD, DD);
    attention<<<gAttn, blk128, 0, stream>>>(Qb, Kb, Vb, Tb);
    sgemm<false, false><<<gN512, blk256, 0, stream>>>(Tb, e_wo + wOff, nullptr, Ab, NT, DD, DD);
    sgemm<false, true ><<<gN2048, blk256, 0, stream>>>(Ab, e_w1 + (size_t)e * DD * FF,
        e_b1 + (size_t)e * FF, MID, NT, FF, DD);
    sgemm<true,  true ><<<gN512, blk256, 0, stream>>>(MID, e_w2 + (size_t)e * FF * DD,
        e_b2 + (size_t)e * DD, AGG, NT, DD, FF);
  }

  // ---------------- final attention ----------------
  sgemm<false, false><<<gN512, blk256, 0, stream>>>(AGG, a_wq, nullptr, Qb, NT, DD, DD);
  sgemm<false, false><<<gN512, blk256, 0, stream>>>(AGG, a_wk, nullptr, Kb, NT, DD, DD);
  sgemm<false, false><<<gN512, blk256, 0, stream>>>(AGG, a_wv, nullptr, Vb, NT, DD, DD);
  attention<<<gAttn, blk128, 0, stream>>>(Qb, Kb, Vb, Tb);
  sgemm<false, false><<<gN512, blk256, 0, stream>>>(Tb, a_wo, nullptr, Ab, NT, DD, DD);

  // ---------------- LSTM ----------------
  // input projection: uses first DD rows of lstm_w (row stride 4L == 512)
  sgemm<false, true ><<<gN512, blk256, 0, stream>>>(Ab, lstm_w, lstm_b, ZX, NT, 4 * LL, DD);
  lstm_scan<<<BB, blk512, 0, stream>>>(ZX, lstm_w, LOUT);

  // ---------------- head ----------------
  final_proj<<<NT / 4, blk256, 0, stream>>>(LOUT, wd, bd, out);
}